// Round 2
// 365.484 us; speedup vs baseline: 1.1012x; 1.1012x over previous
//
#include <hip/hip_runtime.h>

// Problem constants (CRF: B=256 seqs, M=1024 steps, D=128 feat, N=26 labels)
#define CB 256
#define CM 1024
#define CD 128
#define CN 26

__device__ inline float rfl_f(float x) {
    return __int_as_float(__builtin_amdgcn_readfirstlane(__float_as_int(x)));
}
__device__ inline float rdl_f(float x, int lane) {
#if __has_builtin(__builtin_amdgcn_readlane)
    return __int_as_float(__builtin_amdgcn_readlane(__float_as_int(x), lane));
#else
    return __shfl(x, lane, 64);
#endif
}
__device__ inline float fexp2(float x) {
#if __has_builtin(__builtin_amdgcn_exp2f)
    return __builtin_amdgcn_exp2f(x);
#else
    return exp2f(x);
#endif
}
__device__ inline float flog2(float x) {
#if __has_builtin(__builtin_amdgcn_logf)
    return __builtin_amdgcn_logf(x);
#else
    return log2f(x);
#endif
}

// ---------------------------------------------------------------------------
// Kernel 1: emissions E[r, a] = log2(e) * dot(X[r, :], W[a, :])
//   + fused unnorm term: usum = sum_i e[i,y_i] + sum_i T[y_{i-1},y_i]
// Block = 256 threads = 256 rows. W staged in LDS (13 KB, immune to L1
// thrash). X staged in LDS in coalesced 256-row x 32-col slabs (8 full
// 128B lines per load instruction), pitch padded to 36 floats so b128
// LDS ops are 16B-aligned and hit the minimal 8-word/bank aliasing.
// Thread t owns row R0+t, 26-register accumulator. usum uses acc[y]
// directly (no E re-read): 26-way cndmask select, wave reduce, one
// atomic per block.
// ---------------------------------------------------------------------------
__global__ __launch_bounds__(256) void emit_kernel(
    const float* __restrict__ X, const float* __restrict__ W,
    const int* __restrict__ labels, const float* __restrict__ T,
    float* __restrict__ E, float* __restrict__ out) {
    __shared__ float Ws[CN * CD];    // 13312 B
    __shared__ float Xs[256 * 36];   // 36864 B, pitch 36 floats (16B-aligned)
    __shared__ float rsum[4];

    const int t = threadIdx.x;
    const int R0 = blockIdx.x * 256;

    for (int idx = t; idx < CN * CD; idx += 256) Ws[idx] = W[idx];

    float acc[CN];
#pragma unroll
    for (int a = 0; a < CN; ++a) acc[a] = 0.f;

    for (int c = 0; c < 4; ++c) {  // four 32-col slabs of D=128
        __syncthreads();           // covers Ws on c==0, protects Xs reuse after
#pragma unroll
        for (int q = 0; q < 8; ++q) {
            int g = q * 256 + t;
            int row = g >> 3, cv = g & 7;  // 8 float4 per row-slab
            *reinterpret_cast<float4*>(&Xs[row * 36 + cv * 4]) =
                *reinterpret_cast<const float4*>(
                    X + (size_t)(R0 + row) * CD + c * 32 + cv * 4);
        }
        __syncthreads();
        for (int jj = 0; jj < 8; ++jj) {
            float4 xv = *reinterpret_cast<const float4*>(&Xs[t * 36 + jj * 4]);
            const float* wp = &Ws[c * 32 + jj * 4];
#pragma unroll
            for (int a = 0; a < CN; ++a) {
                float4 wv = *reinterpret_cast<const float4*>(wp + a * CD);
                acc[a] = fmaf(xv.x, wv.x, acc[a]);
                acc[a] = fmaf(xv.y, wv.y, acc[a]);
                acc[a] = fmaf(xv.z, wv.z, acc[a]);
                acc[a] = fmaf(xv.w, wv.w, acc[a]);
            }
        }
    }

    // Store E pre-scaled by log2(e): crf step then needs only exp2(e).
    const float LOG2E = 1.4426950408889634f;
    float2* e2 = reinterpret_cast<float2*>(E + (size_t)(R0 + t) * CN);
#pragma unroll
    for (int a = 0; a < CN / 2; ++a)
        e2[a] = make_float2(acc[2 * a] * LOG2E, acc[2 * a + 1] * LOG2E);

    // unnorm contribution of this row (natural-log units, from registers).
    // Static select avoids runtime-indexing acc[] into scratch (rule #20).
    int y = labels[R0 + t];
    float us = acc[0];
#pragma unroll
    for (int a = 1; a < CN; ++a) us = (y == a) ? acc[a] : us;
    if ((R0 + t) & (CM - 1)) {  // not a sequence start
        int yp = labels[R0 + t - 1];
        us += T[yp * CN + y];
    }
#pragma unroll
    for (int off = 32; off > 0; off >>= 1) us += __shfl_xor(us, off, 64);
    if ((t & 63) == 0) rsum[t >> 6] = us;
    __syncthreads();
    if (t == 0)
        atomicAdd(out, (rsum[0] + rsum[1] + rsum[2] + rsum[3]) * (1.f / CB));
}

// ---------------------------------------------------------------------------
// Kernel 2: per-sequence forward recursion, one wave per sequence.
// Layout: lane a in [0,26) holds f[a] (lanes 26..63 duplicate a=25).
// Per step the 26 broadcasts f[b] are wave-uniform -> v_readlane into
// SGPRs consumed directly by v_fmac (no LDS-pipe ops at all).
// E is software-prefetched 8 steps deep (rolling pointer + imm offsets)
// so L2/HBM latency is off the serial chain. No per-step rescale;
// exact power-of-2 renorm every 8 steps (growth bound ~2^40 per window,
// far from overflow).
// ---------------------------------------------------------------------------
__global__ __launch_bounds__(64) void crf_forward_kernel(
    const float* __restrict__ E, const float* __restrict__ T,
    float* __restrict__ out) {
    const int s = blockIdx.x;
    const int l = threadIdx.x;
    const float LN2 = 0.6931471805599453f;

    const int a = (l < CN) ? l : (CN - 1);

    float AT[CN];  // AT[b] = exp(T[b,a])
#pragma unroll
    for (int b = 0; b < CN; ++b) AT[b] = expf(T[b * CN + a]);

    const float* __restrict__ Eb = E + (size_t)s * CM * CN + a;

    float f = fexp2(Eb[0]);  // E already in log2 units
    float L = 0.f;

    float epf[8];  // steps 1..8
#pragma unroll
    for (int k = 0; k < 8; ++k) epf[k] = Eb[(size_t)(1 + k) * CN];
    const float* pf = Eb + (size_t)9 * CN;  // next step to prefetch

    auto step = [&](float e_cur, bool renorm) {
        float p = fexp2(e_cur);  // off the f-dependency chain
        float d0 = 0.f, d1 = 0.f, d2 = 0.f, d3 = 0.f;
#pragma unroll
        for (int b = 0; b < 24; b += 4) {
            d0 = fmaf(AT[b + 0], rdl_f(f, b + 0), d0);
            d1 = fmaf(AT[b + 1], rdl_f(f, b + 1), d1);
            d2 = fmaf(AT[b + 2], rdl_f(f, b + 2), d2);
            d3 = fmaf(AT[b + 3], rdl_f(f, b + 3), d3);
        }
        d0 = fmaf(AT[24], rdl_f(f, 24), d0);
        d1 = fmaf(AT[25], rdl_f(f, 25), d1);
        f = p * ((d0 + d1) + (d2 + d3));
        if (renorm) {  // exact power-of-2: no rounding error
            float fr = rfl_f(f);
            int k2 = (int)((__float_as_uint(fr) >> 23) & 255) - 127;
            f = ldexpf(f, -k2);
            L += (float)k2;
        }
    };

    // Main: 126 x 8 steps = steps 1..1008; prefetch is always in-bounds
    // (max prefetched step = 1009+7 = 1016 on it=125).
    for (int it = 0; it < 126; ++it) {
#pragma unroll
        for (int k = 0; k < 8; ++k) {
            float e_cur = epf[k];
            epf[k] = pf[(size_t)k * CN];  // imm-offset loads, one base ptr
            step(e_cur, k == 7);
        }
        pf += 8 * CN;
    }
    // Mid-tail: steps 1009..1016 (renorm lands on 1016), clamped prefetch.
#pragma unroll
    for (int k = 0; k < 8; ++k) {
        float e_cur = epf[k];
        int nx = (1017 + k > CM - 1) ? (CM - 1) : (1017 + k);
        epf[k] = Eb[(size_t)nx * CN];
        step(e_cur, k == 7);
    }
    // End-tail: steps 1017..1023, no prefetch, no renorm needed.
#pragma unroll
    for (int k = 0; k < 7; ++k) step(epf[k], false);

    // logZ = ln2 * (L + log2(sum_a f[a]))
    float fv = (l < CN) ? f : 0.f;
#pragma unroll
    for (int off = 32; off > 0; off >>= 1) fv += __shfl_xor(fv, off, 64);
    float logZ = LN2 * (L + flog2(fv));
    if (l == 0) atomicAdd(out, -logZ * (1.f / (float)CB));
}

extern "C" void kernel_launch(void* const* d_in, const int* in_sizes, int n_in,
                              void* d_out, int out_size, void* d_ws,
                              size_t ws_size, hipStream_t stream) {
    const float* X = (const float*)d_in[0];   // [B, M, D]
    const int* labels = (const int*)d_in[1];  // [B, M]
    const float* W = (const float*)d_in[2];   // [N, D]
    const float* T = (const float*)d_in[3];   // [N, N]
    float* out = (float*)d_out;               // scalar
    float* E = (float*)d_ws;                  // [B*M, N] emissions (log2 units)

    hipMemsetAsync(d_out, 0, sizeof(float), stream);
    emit_kernel<<<(CB * CM) / 256, 256, 0, stream>>>(X, W, labels, T, E, out);
    crf_forward_kernel<<<CB, 64, 0, stream>>>(E, T, out);
}

// Round 3
// 339.949 us; speedup vs baseline: 1.1839x; 1.0751x over previous
//
#include <hip/hip_runtime.h>

// Problem constants (CRF: B=256 seqs, M=1024 steps, D=128 feat, N=26 labels)
#define CB 256
#define CM 1024
#define CD 128
#define CN 26

__device__ inline float rfl_f(float x) {
    return __int_as_float(__builtin_amdgcn_readfirstlane(__float_as_int(x)));
}
__device__ inline float rdl_f(float x, int lane) {
#if __has_builtin(__builtin_amdgcn_readlane)
    return __int_as_float(__builtin_amdgcn_readlane(__float_as_int(x), lane));
#else
    return __shfl(x, lane, 64);
#endif
}
__device__ inline float fexp2(float x) {
#if __has_builtin(__builtin_amdgcn_exp2f)
    return __builtin_amdgcn_exp2f(x);
#else
    return exp2f(x);
#endif
}
__device__ inline float flog2(float x) {
#if __has_builtin(__builtin_amdgcn_logf)
    return __builtin_amdgcn_logf(x);
#else
    return log2f(x);
#endif
}

// ---------------------------------------------------------------------------
// Kernel 1: emissions E[r, a] = log2(e) * dot(X[r, :], W[a, :])
//   + fused unnorm term: usum = sum_i e[i,y_i] + sum_i T[y_{i-1},y_i]
// Block = 256 threads = 256 rows.
// X: LDS-staged in coalesced 256-row x 32-col slabs (round-2 win, kept).
// W: read DIRECTLY from global with wave-uniform addresses -> compiler
//    emits s_load (K$, scalar pipe). Round 2 showed LDS-staged W was the
//    bottleneck: 832 broadcast ds_read_b128/thread serialized the LDS pipe
//    (~69 us/CU) while VALU sat at 22%. Scalar W costs zero LDS/VALU ops.
// Thread t owns row R0+t; 26-register accumulator; usum from acc[y] via
// 26-way cndmask select; wave reduce; one atomic per block.
// ---------------------------------------------------------------------------
__global__ __launch_bounds__(256) void emit_kernel(
    const float* __restrict__ X, const float* __restrict__ W,
    const int* __restrict__ labels, const float* __restrict__ T,
    float* __restrict__ E, float* __restrict__ out) {
    __shared__ float Xs[256 * 36];  // 36864 B, pitch 36 floats (16B-aligned)
    __shared__ float rsum[4];

    const int t = threadIdx.x;
    const int R0 = blockIdx.x * 256;

    float acc[CN];
#pragma unroll
    for (int a = 0; a < CN; ++a) acc[a] = 0.f;

    for (int c = 0; c < 4; ++c) {  // four 32-col slabs of D=128
        if (c) __syncthreads();    // protect Xs reuse (readers done)
#pragma unroll
        for (int q = 0; q < 8; ++q) {
            int g = q * 256 + t;
            int row = g >> 3, cv = g & 7;  // 8 float4 per row-slab
            *reinterpret_cast<float4*>(&Xs[row * 36 + cv * 4]) =
                *reinterpret_cast<const float4*>(
                    X + (size_t)(R0 + row) * CD + c * 32 + cv * 4);
        }
        __syncthreads();

        float4 xv[8];  // this thread's row slab -> registers once
#pragma unroll
        for (int jj = 0; jj < 8; ++jj)
            xv[jj] = *reinterpret_cast<const float4*>(&Xs[t * 36 + jj * 4]);

#pragma unroll
        for (int a = 0; a < CN; ++a) {
            const float* wp = W + a * CD + c * 32;  // wave-uniform -> s_load
#pragma unroll
            for (int jj = 0; jj < 8; ++jj) {
                float4 wv = *reinterpret_cast<const float4*>(wp + jj * 4);
                acc[a] = fmaf(xv[jj].x, wv.x, acc[a]);
                acc[a] = fmaf(xv[jj].y, wv.y, acc[a]);
                acc[a] = fmaf(xv[jj].z, wv.z, acc[a]);
                acc[a] = fmaf(xv[jj].w, wv.w, acc[a]);
            }
        }
    }

    // Store E pre-scaled by log2(e): crf step then needs only exp2(e).
    const float LOG2E = 1.4426950408889634f;
    float2* e2 = reinterpret_cast<float2*>(E + (size_t)(R0 + t) * CN);
#pragma unroll
    for (int a = 0; a < CN / 2; ++a)
        e2[a] = make_float2(acc[2 * a] * LOG2E, acc[2 * a + 1] * LOG2E);

    // unnorm contribution of this row (natural-log units, from registers).
    // Static select avoids runtime-indexing acc[] into scratch (rule #20).
    int y = labels[R0 + t];
    float us = acc[0];
#pragma unroll
    for (int a = 1; a < CN; ++a) us = (y == a) ? acc[a] : us;
    if ((R0 + t) & (CM - 1)) {  // not a sequence start
        int yp = labels[R0 + t - 1];
        us += T[yp * CN + y];
    }
#pragma unroll
    for (int off = 32; off > 0; off >>= 1) us += __shfl_xor(us, off, 64);
    if ((t & 63) == 0) rsum[t >> 6] = us;
    __syncthreads();
    if (t == 0)
        atomicAdd(out, (rsum[0] + rsum[1] + rsum[2] + rsum[3]) * (1.f / CB));
}

// ---------------------------------------------------------------------------
// Kernel 2: per-sequence forward recursion, one wave per sequence.
// Layout: lane a in [0,26) holds f[a] (lanes 26..63 duplicate a=25).
// Per step the 26 broadcasts f[b] are wave-uniform -> v_readlane into
// SGPRs consumed directly by v_fmac (no LDS-pipe ops).
// E is software-prefetched 16 steps deep (round-3 change: was 8; round-0
// counters showed the chain is ~75% memory stall, and 8 steps ~ 1000 cyc
// only marginally covers L3/HBM latency).
// Exact power-of-2 renorm every 8 steps.
// ---------------------------------------------------------------------------
__global__ __launch_bounds__(64) void crf_forward_kernel(
    const float* __restrict__ E, const float* __restrict__ T,
    float* __restrict__ out) {
    const int s = blockIdx.x;
    const int l = threadIdx.x;
    const float LN2 = 0.6931471805599453f;

    const int a = (l < CN) ? l : (CN - 1);

    float AT[CN];  // AT[b] = exp(T[b,a])
#pragma unroll
    for (int b = 0; b < CN; ++b) AT[b] = expf(T[b * CN + a]);

    const float* __restrict__ Eb = E + (size_t)s * CM * CN + a;

    float f = fexp2(Eb[0]);  // E already in log2 units
    float L = 0.f;

    float epf[16];  // steps 1..16
#pragma unroll
    for (int k = 0; k < 16; ++k) epf[k] = Eb[(size_t)(1 + k) * CN];
    const float* pf = Eb + (size_t)17 * CN;  // next step to prefetch

    auto step = [&](float e_cur, bool renorm) {
        float p = fexp2(e_cur);  // off the f-dependency chain
        float d0 = 0.f, d1 = 0.f, d2 = 0.f, d3 = 0.f;
#pragma unroll
        for (int b = 0; b < 24; b += 4) {
            d0 = fmaf(AT[b + 0], rdl_f(f, b + 0), d0);
            d1 = fmaf(AT[b + 1], rdl_f(f, b + 1), d1);
            d2 = fmaf(AT[b + 2], rdl_f(f, b + 2), d2);
            d3 = fmaf(AT[b + 3], rdl_f(f, b + 3), d3);
        }
        d0 = fmaf(AT[24], rdl_f(f, 24), d0);
        d1 = fmaf(AT[25], rdl_f(f, 25), d1);
        f = p * ((d0 + d1) + (d2 + d3));
        if (renorm) {  // exact power-of-2: no rounding error
            float fr = rfl_f(f);
            int k2 = (int)((__float_as_uint(fr) >> 23) & 255) - 127;
            f = ldexpf(f, -k2);
            L += (float)k2;
        }
    };

    // Main: 62 x 16 steps = steps 1..992; during it, prefetch steps
    // 17+16*it .. 32+16*it (max 1008 at it=61, always in-bounds).
    for (int it = 0; it < 62; ++it) {
#pragma unroll
        for (int k = 0; k < 16; ++k) {
            float e_cur = epf[k];
            epf[k] = pf[(size_t)k * CN];  // imm-offset loads, one base ptr
            step(e_cur, (k & 7) == 7);
        }
        pf += 16 * CN;
    }
    // Mid-tail: steps 993..1008 (renorm at 1000, 1008), clamped prefetch
    // of steps 1009..1023 (epf[15] clamps to 1023, never consumed).
#pragma unroll
    for (int k = 0; k < 16; ++k) {
        float e_cur = epf[k];
        int nx = (1009 + k > CM - 1) ? (CM - 1) : (1009 + k);
        epf[k] = Eb[(size_t)nx * CN];
        step(e_cur, (k & 7) == 7);
    }
    // End-tail: steps 1009..1023 (15 steps), renorm at 1016 (k==7) so the
    // unrenormalized run never exceeds 8 steps.
#pragma unroll
    for (int k = 0; k < 15; ++k) step(epf[k], k == 7);

    // logZ = ln2 * (L + log2(sum_a f[a]))
    float fv = (l < CN) ? f : 0.f;
#pragma unroll
    for (int off = 32; off > 0; off >>= 1) fv += __shfl_xor(fv, off, 64);
    float logZ = LN2 * (L + flog2(fv));
    if (l == 0) atomicAdd(out, -logZ * (1.f / (float)CB));
}

extern "C" void kernel_launch(void* const* d_in, const int* in_sizes, int n_in,
                              void* d_out, int out_size, void* d_ws,
                              size_t ws_size, hipStream_t stream) {
    const float* X = (const float*)d_in[0];   // [B, M, D]
    const int* labels = (const int*)d_in[1];  // [B, M]
    const float* W = (const float*)d_in[2];   // [N, D]
    const float* T = (const float*)d_in[3];   // [N, N]
    float* out = (float*)d_out;               // scalar
    float* E = (float*)d_ws;                  // [B*M, N] emissions (log2 units)

    hipMemsetAsync(d_out, 0, sizeof(float), stream);
    emit_kernel<<<(CB * CM) / 256, 256, 0, stream>>>(X, W, labels, T, E, out);
    crf_forward_kernel<<<CB, 64, 0, stream>>>(E, T, out);
}